// Round 4
// baseline (9015.663 us; speedup 1.0000x reference)
//
#include <hip/hip_runtime.h>

#define T_SEQ   32
#define N_NODES 10000
#define E_EDGES 160000
#define EF      (E_EDGES + N_NODES)
#define IN_CH   128
#define HID     64
#define HEADS   8
#define HC      512
#define GRU_H   256
#define G3      768

typedef __attribute__((ext_vector_type(8))) short short8;
typedef __attribute__((ext_vector_type(4))) float f32x4;
typedef unsigned short ushort_t;

__device__ __forceinline__ float wave_reduce_sum(float v){
#pragma unroll
  for (int off = 32; off; off >>= 1) v += __shfl_xor(v, off, 64);
  return v;
}

__device__ __forceinline__ ushort_t f2bf(float v){
  unsigned u = __float_as_uint(v);
  unsigned r = u + 0x7FFFu + ((u >> 16) & 1u);
  return (ushort_t)(r >> 16);
}
__device__ __forceinline__ float bf2f(ushort_t b){
  return __uint_as_float(((unsigned)b) << 16);
}

// ---------------- graph setup ----------------

__global__ __launch_bounds__(256)
void deg_loop_kernel(const int* __restrict__ edst, const float* __restrict__ eattr,
                     int* __restrict__ deg, float* __restrict__ lsum){
  int e = blockIdx.x * 256 + threadIdx.x;
  if (e < E_EDGES){
    int d = edst[e];
    atomicAdd(&deg[d], 1);
    atomicAdd(&lsum[d*3+0], eattr[e*3+0]);
    atomicAdd(&lsum[d*3+1], eattr[e*3+1]);
    atomicAdd(&lsum[d*3+2], eattr[e*3+2]);
  }
}

__global__ __launch_bounds__(256)
void loop_div_kernel(const int* __restrict__ deg, const float* __restrict__ lsum,
                     float* __restrict__ lattr){
  int n = blockIdx.x * 256 + threadIdx.x;
  if (n < N_NODES){
    float d = fmaxf((float)deg[n], 1.0f);
    lattr[n*3+0] = lsum[n*3+0] / d;
    lattr[n*3+1] = lsum[n*3+1] / d;
    lattr[n*3+2] = lsum[n*3+2] / d;
  }
}

__global__ __launch_bounds__(256)
void scan_rowptr_kernel(const int* __restrict__ deg, int* __restrict__ row_ptr){
  __shared__ int sums[256];
  __shared__ int base[256];
  int tid = threadIdx.x;
  const int CH = 40;
  int start = tid * CH;
  int s = 0;
  for (int k = 0; k < CH; k++){
    int n = start + k;
    if (n < N_NODES) s += deg[n];
  }
  sums[tid] = s;
  __syncthreads();
  if (tid == 0){
    int acc = 0;
    for (int i = 0; i < 256; i++){ base[i] = acc; acc += sums[i]; }
  }
  __syncthreads();
  int acc = base[tid];
  for (int k = 0; k < CH; k++){
    int n = start + k;
    if (n < N_NODES){ row_ptr[n] = acc; acc += deg[n]; }
    else if (n == N_NODES){ row_ptr[n] = acc; }
  }
}

__global__ __launch_bounds__(256)
void csr_fill_kernel(const int* __restrict__ edst, const int* __restrict__ row_ptr,
                     int* __restrict__ cursor, int* __restrict__ col){
  int e = blockIdx.x * 256 + threadIdx.x;
  if (e < E_EDGES){
    int d = edst[e];
    int pos = row_ptr[d] + atomicAdd(&cursor[d], 1);
    col[pos] = e;
  }
}

__global__ __launch_bounds__(256)
void build_emeta(const float* __restrict__ eattr, const float* __restrict__ lattr,
                 const int* __restrict__ esrc, float4* __restrict__ emeta){
  int e = blockIdx.x * 256 + threadIdx.x;
  if (e < E_EDGES){
    emeta[e] = make_float4(eattr[e*3], eattr[e*3+1], eattr[e*3+2], __int_as_float(esrc[e]));
  } else if (e < EF){
    int n = e - E_EDGES;
    emeta[e] = make_float4(lattr[n*3], lattr[n*3+1], lattr[n*3+2], __int_as_float(n));
  }
}

// ---------------- pre-split kernels ----------------

__global__ __launch_bounds__(256)
void split_arr(const float* __restrict__ src, ushort_t* __restrict__ hi,
               ushort_t* __restrict__ lo, long n){
  long idx = (long)blockIdx.x * 256 + threadIdx.x;
  if (idx < n){
    float v = src[idx];
    ushort_t h = f2bf(v);
    hi[idx] = h; lo[idx] = f2bf(v - bf2f(h));
  }
}

// GAT1 weights: [wl | wr] : [128][1024] -> [n][k] n<1024, k<128
__global__ __launch_bounds__(256)
void split_w_gat1(const float* __restrict__ wl, const float* __restrict__ wr,
                  ushort_t* __restrict__ hi, ushort_t* __restrict__ lo){
  int idx = blockIdx.x * 256 + threadIdx.x;
  if (idx >= 1024 * 128) return;
  int n = idx >> 7, k = idx & 127;
  float v = (n < 512) ? wl[k * 512 + n] : wr[k * 512 + (n - 512)];
  ushort_t h = f2bf(v);
  hi[idx] = h; lo[idx] = f2bf(v - bf2f(h));
}

// GAT2 weights: [wl2 | wr2] : [512][128] -> [n][k] n<128, k<512
__global__ __launch_bounds__(256)
void split_w_gat2(const float* __restrict__ wl, const float* __restrict__ wr,
                  ushort_t* __restrict__ hi, ushort_t* __restrict__ lo){
  int idx = blockIdx.x * 256 + threadIdx.x;
  if (idx >= 128 * 512) return;
  int n = idx >> 9, k = idx & 511;
  float v = (n < 64) ? wl[k * 64 + n] : wr[k * 64 + (n - 64)];
  ushort_t h = f2bf(v);
  hi[idx] = h; lo[idx] = f2bf(v - bf2f(h));
}

// GRU: Wg[n][k] = k<64 ? wih[n][k] : whh[n][k-64]; [768][320]
__global__ __launch_bounds__(256)
void split_w_gru(const float* __restrict__ wih, const float* __restrict__ whh,
                 ushort_t* __restrict__ hi, ushort_t* __restrict__ lo){
  int idx = blockIdx.x * 256 + threadIdx.x;
  if (idx >= G3 * 320) return;
  int n = idx / 320, k = idx - n * 320;
  float v = (k < 64) ? wih[n * 64 + k] : whh[n * 256 + (k - 64)];
  ushort_t h = f2bf(v);
  hi[idx] = h; lo[idx] = f2bf(v - bf2f(h));
}

// ------------- barrier-free bf16x3 GEMM: C[M,N] = A @ B^T ------------------
// A pre-split [M][K] (hi,lo); B pre-split [N][K] (hi,lo); C fp32 [M][N].
// Wave tile: 32 rows x 64 cols; fragments loaded directly from global (L2-hot).

__global__ __launch_bounds__(256)
void gemm_nolds(const ushort_t* __restrict__ Ah, const ushort_t* __restrict__ Al,
                const ushort_t* __restrict__ Bh, const ushort_t* __restrict__ Bl,
                float* __restrict__ C, int M, int K, int N){
  int tid = threadIdx.x;
  int w = tid >> 6, lane = tid & 63;
  int m16 = lane & 15, quad = lane >> 4;
  int n0 = (blockIdx.y * 4 + w) * 64;
  if (n0 >= N) return;
  int m0 = blockIdx.x * 32;

  f32x4 acc[2][4];
#pragma unroll
  for (int i = 0; i < 2; i++)
#pragma unroll
    for (int j = 0; j < 4; j++) acc[i][j] = (f32x4){0,0,0,0};

  int ar0 = m0 + m16;      if (ar0 >= M) ar0 = M - 1;
  int ar1 = m0 + 16 + m16; if (ar1 >= M) ar1 = M - 1;
  const ushort_t* Ah0 = Ah + (size_t)ar0 * K + quad * 8;
  const ushort_t* Al0 = Al + (size_t)ar0 * K + quad * 8;
  const ushort_t* Ah1 = Ah + (size_t)ar1 * K + quad * 8;
  const ushort_t* Al1 = Al + (size_t)ar1 * K + quad * 8;

  for (int k0 = 0; k0 < K; k0 += 32){
    short8 a_h[2], a_l[2];
    a_h[0] = *(const short8*)(Ah0 + k0); a_l[0] = *(const short8*)(Al0 + k0);
    a_h[1] = *(const short8*)(Ah1 + k0); a_l[1] = *(const short8*)(Al1 + k0);
#pragma unroll
    for (int nt = 0; nt < 4; nt++){
      size_t boff = (size_t)(n0 + nt * 16 + m16) * K + k0 + quad * 8;
      short8 b_h = *(const short8*)(Bh + boff);
      short8 b_l = *(const short8*)(Bl + boff);
#pragma unroll
      for (int mt = 0; mt < 2; mt++){
        acc[mt][nt] = __builtin_amdgcn_mfma_f32_16x16x32_bf16(a_h[mt], b_h, acc[mt][nt],0,0,0);
        acc[mt][nt] = __builtin_amdgcn_mfma_f32_16x16x32_bf16(a_h[mt], b_l, acc[mt][nt],0,0,0);
        acc[mt][nt] = __builtin_amdgcn_mfma_f32_16x16x32_bf16(a_l[mt], b_h, acc[mt][nt],0,0,0);
      }
    }
  }
#pragma unroll
  for (int mt = 0; mt < 2; mt++){
    int row = m0 + mt * 16 + quad * 4;
#pragma unroll
    for (int nt = 0; nt < 4; nt++){
      int cc = n0 + nt * 16 + m16;
#pragma unroll
      for (int r4 = 0; r4 < 4; r4++){
        if (row + r4 < M) C[(size_t)(row + r4) * N + cc] = acc[mt][nt][r4];
      }
    }
  }
}

// ------------- barrier-free fused GRU step, both directions ---------------

struct GruArgs {
  const ushort_t *EtH[2], *EtL[2];
  const ushort_t *WH[2],  *WL[2];
  const float    *BIH[2], *BHH[2];
  const ushort_t *HinH[2],*HinL[2];
  ushort_t *HoutH[2], *HoutL[2];
};

__global__ __launch_bounds__(256)
void gru_nolds(GruArgs ga){
  int dir = blockIdx.z;
  const ushort_t* EtH  = ga.EtH[dir];  const ushort_t* EtL  = ga.EtL[dir];
  const ushort_t* WH   = ga.WH[dir];   const ushort_t* WL   = ga.WL[dir];
  const float*    BIH  = ga.BIH[dir];  const float*    BHH  = ga.BHH[dir];
  const ushort_t* HinH = ga.HinH[dir]; const ushort_t* HinL = ga.HinL[dir];
  ushort_t* HoutH = ga.HoutH[dir];     ushort_t* HoutL = ga.HoutL[dir];

  int tid = threadIdx.x;
  int w = tid >> 6, lane = tid & 63;
  int m16 = lane & 15, quad = lane >> 4;
  int j0 = (blockIdx.y * 4 + w) * 32;      // 8 j-tiles of 32 -> 256
  int m0 = blockIdx.x * 32;

  int ar0 = m0 + m16;      if (ar0 >= N_NODES) ar0 = N_NODES - 1;
  int ar1 = m0 + 16 + m16; if (ar1 >= N_NODES) ar1 = N_NODES - 1;

  // acc[gate-part][mt][nt]: 0=r, 1=z, 2=n_input, 3=n_hidden
  f32x4 acc[4][2][2];
#pragma unroll
  for (int g = 0; g < 4; g++)
#pragma unroll
    for (int i = 0; i < 2; i++)
#pragma unroll
      for (int j = 0; j < 2; j++) acc[g][i][j] = (f32x4){0,0,0,0};

  for (int k0 = 0; k0 < 320; k0 += 32){
    short8 a_h[2], a_l[2];
    if (k0 < 64){
      a_h[0] = *(const short8*)(EtH + (size_t)ar0 * 64 + k0 + quad * 8);
      a_l[0] = *(const short8*)(EtL + (size_t)ar0 * 64 + k0 + quad * 8);
      a_h[1] = *(const short8*)(EtH + (size_t)ar1 * 64 + k0 + quad * 8);
      a_l[1] = *(const short8*)(EtL + (size_t)ar1 * 64 + k0 + quad * 8);
    } else {
      a_h[0] = *(const short8*)(HinH + (size_t)ar0 * 256 + (k0 - 64) + quad * 8);
      a_l[0] = *(const short8*)(HinL + (size_t)ar0 * 256 + (k0 - 64) + quad * 8);
      a_h[1] = *(const short8*)(HinH + (size_t)ar1 * 256 + (k0 - 64) + quad * 8);
      a_l[1] = *(const short8*)(HinL + (size_t)ar1 * 256 + (k0 - 64) + quad * 8);
    }
#pragma unroll
    for (int g = 0; g < 3; g++){
      int tgt = (g < 2) ? g : (k0 < 64 ? 2 : 3);
#pragma unroll
      for (int nt = 0; nt < 2; nt++){
        size_t boff = (size_t)(g * GRU_H + j0 + nt * 16 + m16) * 320 + k0 + quad * 8;
        short8 b_h = *(const short8*)(WH + boff);
        short8 b_l = *(const short8*)(WL + boff);
#pragma unroll
        for (int mt = 0; mt < 2; mt++){
          acc[tgt][mt][nt] = __builtin_amdgcn_mfma_f32_16x16x32_bf16(a_h[mt], b_h, acc[tgt][mt][nt],0,0,0);
          acc[tgt][mt][nt] = __builtin_amdgcn_mfma_f32_16x16x32_bf16(a_h[mt], b_l, acc[tgt][mt][nt],0,0,0);
          acc[tgt][mt][nt] = __builtin_amdgcn_mfma_f32_16x16x32_bf16(a_l[mt], b_h, acc[tgt][mt][nt],0,0,0);
        }
      }
    }
  }

#pragma unroll
  for (int mt = 0; mt < 2; mt++){
    int row = m0 + mt * 16 + quad * 4;
#pragma unroll
    for (int nt = 0; nt < 2; nt++){
      int j = j0 + nt * 16 + m16;
      float br  = BIH[j] + BHH[j];
      float bz  = BIH[GRU_H + j] + BHH[GRU_H + j];
      float bni = BIH[2*GRU_H + j];
      float bnh = BHH[2*GRU_H + j];
#pragma unroll
      for (int r4 = 0; r4 < 4; r4++){
        int node = row + r4;
        if (node < N_NODES){
          float rr = 1.f / (1.f + __expf(-(acc[0][mt][nt][r4] + br)));
          float zz = 1.f / (1.f + __expf(-(acc[1][mt][nt][r4] + bz)));
          float nn = tanhf(acc[2][mt][nt][r4] + bni + rr * (acc[3][mt][nt][r4] + bnh));
          size_t hidx = (size_t)node * GRU_H + j;
          float hold = bf2f(HinH[hidx]) + bf2f(HinL[hidx]);
          float hv = (1.f - zz) * nn + zz * hold;
          ushort_t hh = f2bf(hv);
          HoutH[hidx] = hh;
          HoutL[hidx] = f2bf(hv - bf2f(hh));
        }
      }
    }
  }
}

// ---------------- fused GAT layer 1 ----------------

__global__ __launch_bounds__(256)
void gat1_fused(const float* __restrict__ xlr, const float4* __restrict__ emeta,
                const int* __restrict__ row_ptr, const int* __restrict__ col,
                const float* __restrict__ we, const float* __restrict__ att,
                const float* __restrict__ bias,
                ushort_t* __restrict__ outh, ushort_t* __restrict__ outl){
  int n = (blockIdx.x * 256 + threadIdx.x) >> 6;
  int lane = threadIdx.x & 63;
  if (n >= N_NODES) return;
  int ch0 = lane * 4;
  int ch1 = 256 + lane * 4;

  float4 att0 = *(const float4*)&att[ch0];
  float4 att1 = *(const float4*)&att[ch1];
  float4 we00 = *(const float4*)&we[ch0],        we01 = *(const float4*)&we[ch1];
  float4 we10 = *(const float4*)&we[512 + ch0],  we11 = *(const float4*)&we[512 + ch1];
  float4 we20 = *(const float4*)&we[1024 + ch0], we21 = *(const float4*)&we[1024 + ch1];
  const float* xrow_n = xlr + (size_t)n * 1024;
  float4 xr0 = *(const float4*)&xrow_n[512 + ch0];
  float4 xr1 = *(const float4*)&xrow_n[512 + ch1];

  float den0 = 0.f, den1 = 0.f;
  float4 acc0 = make_float4(0,0,0,0), acc1 = make_float4(0,0,0,0);
  int beg = row_ptr[n], end = row_ptr[n + 1];

  float4 mt_c = emeta[E_EDGES + n];   // self loop first
  for (int p = beg - 1; p < end; p++){
    float4 mt_n = mt_c;
    if (p + 1 < end) mt_n = emeta[col[p + 1]];   // prefetch next meta
    float a0 = mt_c.x, a1 = mt_c.y, a2 = mt_c.z;
    int s = __float_as_int(mt_c.w);
    const float* xrow = xlr + (size_t)s * 1024;
    float4 xl0 = *(const float4*)&xrow[ch0];
    float4 xl1 = *(const float4*)&xrow[ch1];
    {
      float vx = xl0.x + xr0.x + a0*we00.x + a1*we10.x + a2*we20.x;
      float vy = xl0.y + xr0.y + a0*we00.y + a1*we10.y + a2*we20.y;
      float vz = xl0.z + xr0.z + a0*we00.z + a1*we10.z + a2*we20.z;
      float vw = xl0.w + xr0.w + a0*we00.w + a1*we10.w + a2*we20.w;
      vx = fmaxf(vx, 0.2f*vx); vy = fmaxf(vy, 0.2f*vy);
      vz = fmaxf(vz, 0.2f*vz); vw = fmaxf(vw, 0.2f*vw);
      float pm = vx*att0.x + vy*att0.y + vz*att0.z + vw*att0.w;
      pm += __shfl_xor(pm, 1, 64); pm += __shfl_xor(pm, 2, 64);
      pm += __shfl_xor(pm, 4, 64); pm += __shfl_xor(pm, 8, 64);
      float wgt = __expf(pm);
      den0 += wgt;
      acc0.x += wgt * xl0.x; acc0.y += wgt * xl0.y;
      acc0.z += wgt * xl0.z; acc0.w += wgt * xl0.w;
    }
    {
      float vx = xl1.x + xr1.x + a0*we01.x + a1*we11.x + a2*we21.x;
      float vy = xl1.y + xr1.y + a0*we01.y + a1*we11.y + a2*we21.y;
      float vz = xl1.z + xr1.z + a0*we01.z + a1*we11.z + a2*we21.z;
      float vw = xl1.w + xr1.w + a0*we01.w + a1*we11.w + a2*we21.w;
      vx = fmaxf(vx, 0.2f*vx); vy = fmaxf(vy, 0.2f*vy);
      vz = fmaxf(vz, 0.2f*vz); vw = fmaxf(vw, 0.2f*vw);
      float pm = vx*att1.x + vy*att1.y + vz*att1.z + vw*att1.w;
      pm += __shfl_xor(pm, 1, 64); pm += __shfl_xor(pm, 2, 64);
      pm += __shfl_xor(pm, 4, 64); pm += __shfl_xor(pm, 8, 64);
      float wgt = __expf(pm);
      den1 += wgt;
      acc1.x += wgt * xl1.x; acc1.y += wgt * xl1.y;
      acc1.z += wgt * xl1.z; acc1.w += wgt * xl1.w;
    }
    mt_c = mt_n;
  }

  float4 b0 = *(const float4*)&bias[ch0];
  float4 b1 = *(const float4*)&bias[ch1];
  float id0 = 1.f / den0, id1 = 1.f / den1;
  float o[8];
  o[0] = acc0.x*id0 + b0.x; o[1] = acc0.y*id0 + b0.y;
  o[2] = acc0.z*id0 + b0.z; o[3] = acc0.w*id0 + b0.w;
  o[4] = acc1.x*id1 + b1.x; o[5] = acc1.y*id1 + b1.y;
  o[6] = acc1.z*id1 + b1.z; o[7] = acc1.w*id1 + b1.w;
  ushort4 h0, h1v, l0, l1v;
  ushort_t* hp0 = (ushort_t*)&h0; ushort_t* hp1 = (ushort_t*)&h1v;
  ushort_t* lp0 = (ushort_t*)&l0; ushort_t* lp1 = (ushort_t*)&l1v;
#pragma unroll
  for (int i = 0; i < 8; i++){
    float v = o[i];
    v = v > 0.f ? v : (__expf(v) - 1.f);   // ELU
    ushort_t hh = f2bf(v);
    ushort_t ll = f2bf(v - bf2f(hh));
    if (i < 4){ hp0[i] = hh; lp0[i] = ll; } else { hp1[i-4] = hh; lp1[i-4] = ll; }
  }
  *(ushort4*)&outh[(size_t)n * 512 + ch0] = h0;
  *(ushort4*)&outh[(size_t)n * 512 + ch1] = h1v;
  *(ushort4*)&outl[(size_t)n * 512 + ch0] = l0;
  *(ushort4*)&outl[(size_t)n * 512 + ch1] = l1v;
}

// ---------------- fused GAT layer 2 ----------------

__global__ __launch_bounds__(256)
void gat2_fused(const float* __restrict__ xlr, const float4* __restrict__ emeta,
                const int* __restrict__ row_ptr, const int* __restrict__ col,
                const float* __restrict__ we, const float* __restrict__ att,
                const float* __restrict__ bias,
                ushort_t* __restrict__ outh, ushort_t* __restrict__ outl){
  int n = (blockIdx.x * 256 + threadIdx.x) >> 6;
  int lane = threadIdx.x & 63;
  if (n >= N_NODES) return;
  int g = lane >> 4;
  int c4 = (lane & 15) * 4;

  float4 attq = *(const float4*)&att[c4];
  float4 we0q = *(const float4*)&we[c4];
  float4 we1q = *(const float4*)&we[64 + c4];
  float4 we2q = *(const float4*)&we[128 + c4];
  float4 xr4  = *(const float4*)&xlr[(size_t)n * 128 + 64 + c4];

  float den = 0.f;
  float4 acc = make_float4(0,0,0,0);
  int beg = row_ptr[n], end = row_ptr[n + 1];

  for (int p0 = beg - 1; p0 < end; p0 += 4){
    int pp = p0 + g;
    bool valid = pp < end;
    int s = n; float a0 = 0.f, a1 = 0.f, a2 = 0.f;
    if (valid){
      float4 mt = (pp < beg) ? emeta[E_EDGES + n] : emeta[col[pp]];
      a0 = mt.x; a1 = mt.y; a2 = mt.z; s = __float_as_int(mt.w);
    }
    float4 xl4 = *(const float4*)&xlr[(size_t)s * 128 + c4];
    float vx = xl4.x + xr4.x + a0*we0q.x + a1*we1q.x + a2*we2q.x;
    float vy = xl4.y + xr4.y + a0*we0q.y + a1*we1q.y + a2*we2q.y;
    float vz = xl4.z + xr4.z + a0*we0q.z + a1*we1q.z + a2*we2q.z;
    float vw = xl4.w + xr4.w + a0*we0q.w + a1*we1q.w + a2*we2q.w;
    vx = fmaxf(vx, 0.2f*vx); vy = fmaxf(vy, 0.2f*vy);
    vz = fmaxf(vz, 0.2f*vz); vw = fmaxf(vw, 0.2f*vw);
    float pm = vx*attq.x + vy*attq.y + vz*attq.z + vw*attq.w;
    pm += __shfl_xor(pm, 1, 64); pm += __shfl_xor(pm, 2, 64);
    pm += __shfl_xor(pm, 4, 64); pm += __shfl_xor(pm, 8, 64);
    float wgt = valid ? __expf(pm) : 0.f;
    den += wgt;
    acc.x += wgt * xl4.x; acc.y += wgt * xl4.y;
    acc.z += wgt * xl4.z; acc.w += wgt * xl4.w;
  }
#pragma unroll
  for (int off = 16; off <= 32; off <<= 1){
    den   += __shfl_xor(den, off, 64);
    acc.x += __shfl_xor(acc.x, off, 64);
    acc.y += __shfl_xor(acc.y, off, 64);
    acc.z += __shfl_xor(acc.z, off, 64);
    acc.w += __shfl_xor(acc.w, off, 64);
  }
  if (g == 0){
    float4 bq = *(const float4*)&bias[c4];
    float id = 1.f / den;
    float o[4];
    o[0] = acc.x*id + bq.x; o[1] = acc.y*id + bq.y;
    o[2] = acc.z*id + bq.z; o[3] = acc.w*id + bq.w;
    ushort4 hv, lv;
    ushort_t* hp = (ushort_t*)&hv; ushort_t* lp = (ushort_t*)&lv;
#pragma unroll
    for (int i = 0; i < 4; i++){
      float v = o[i];
      v = v > 0.f ? v : (__expf(v) - 1.f);
      ushort_t hh = f2bf(v);
      hp[i] = hh; lp[i] = f2bf(v - bf2f(hh));
    }
    *(ushort4*)&outh[(size_t)n * 64 + c4] = hv;
    *(ushort4*)&outl[(size_t)n * 64 + c4] = lv;
  }
}

// ---------------- tail ----------------

__global__ __launch_bounds__(256)
void mean_kernel(const ushort_t* __restrict__ hfh, const ushort_t* __restrict__ hfl,
                 const ushort_t* __restrict__ hbh, const ushort_t* __restrict__ hbl,
                 float* __restrict__ g){
  int k = threadIdx.x;
  int n0 = blockIdx.x * 50;
  int n1 = n0 + 50; if (n1 > N_NODES) n1 = N_NODES;
  float sf = 0.f, sb = 0.f;
  for (int n = n0; n < n1; n++){
    size_t i = (size_t)n * GRU_H + k;
    sf += bf2f(hfh[i]) + bf2f(hfl[i]);
    sb += bf2f(hbh[i]) + bf2f(hbl[i]);
  }
  atomicAdd(&g[k], sf);
  atomicAdd(&g[GRU_H + k], sb);
}

__global__ __launch_bounds__(64)
void fc_kernel(const float* __restrict__ g, const float* __restrict__ W,
               const float* __restrict__ b, float* __restrict__ out){
  int j = blockIdx.x;
  int lane = threadIdx.x;
  float s = 0.f;
  for (int k = lane; k < 2 * GRU_H; k += 64) s += g[k] * W[j * (2 * GRU_H) + k];
  s = wave_reduce_sum(s);
  if (lane == 0) out[j] = b[j] + s * (1.0f / N_NODES);
}

// ---------------- launch ----------------

extern "C" void kernel_launch(void* const* d_in, const int* in_sizes, int n_in,
                              void* d_out, int out_size, void* d_ws, size_t ws_size,
                              hipStream_t stream){
  const float* x     = (const float*)d_in[0];
  const float* eattr = (const float*)d_in[1];
  const int*   esrc  = (const int*)  d_in[2];
  const int*   edst  = (const int*)  d_in[3];
  const float* g1_wl = (const float*)d_in[4];
  const float* g1_wr = (const float*)d_in[5];
  const float* g1_we = (const float*)d_in[6];
  const float* g1_att= (const float*)d_in[7];
  const float* g1_b  = (const float*)d_in[8];
  const float* g2_wl = (const float*)d_in[9];
  const float* g2_wr = (const float*)d_in[10];
  const float* g2_we = (const float*)d_in[11];
  const float* g2_att= (const float*)d_in[12];
  const float* g2_b  = (const float*)d_in[13];
  const float* wih_f = (const float*)d_in[14];
  const float* whh_f = (const float*)d_in[15];
  const float* bih_f = (const float*)d_in[16];
  const float* bhh_f = (const float*)d_in[17];
  const float* wih_b = (const float*)d_in[18];
  const float* whh_b = (const float*)d_in[19];
  const float* bih_b = (const float*)d_in[20];
  const float* bhh_b = (const float*)d_in[21];
  const float* fc_w  = (const float*)d_in[22];
  const float* fc_b  = (const float*)d_in[23];
  float* out = (float*)d_out;

  float* ws = (float*)d_ws;
  size_t o = 0;
  auto alloc = [&](size_t nfloats) -> float* {
    float* p = ws + o; o += (nfloats + 3) & ~(size_t)3; return p;
  };
  const size_t XTOT = (size_t)T_SEQ * N_NODES * IN_CH;   // 40.96M elems
  ushort_t* xh   = (ushort_t*)alloc(XTOT / 2);
  ushort_t* xlo  = (ushort_t*)alloc(XTOT / 2);
  float* xlr1    = alloc((size_t)N_NODES * 1024);
  ushort_t* h1h  = (ushort_t*)alloc((size_t)N_NODES * 512 / 2 + 4);
  ushort_t* h1l  = (ushort_t*)alloc((size_t)N_NODES * 512 / 2 + 4);
  const size_t ETOT = (size_t)T_SEQ * N_NODES * HID;     // 20.48M elems
  ushort_t* embh = (ushort_t*)alloc(ETOT / 2);
  ushort_t* embl = (ushort_t*)alloc(ETOT / 2);
  const size_t HTOT = (size_t)N_NODES * GRU_H;           // 2.56M elems
  ushort_t* hbuf[8];
  for (int i = 0; i < 8; i++) hbuf[i] = (ushort_t*)alloc(HTOT / 2 + 4);
  float* lsum  = alloc((size_t)N_NODES * 3);
  float* lattr = alloc((size_t)N_NODES * 3);
  float* gmean = alloc(512);
  float4* emeta = (float4*)alloc((size_t)EF * 4);
  ushort_t* W1h = (ushort_t*)alloc(1024*128/2);
  ushort_t* W1l = (ushort_t*)alloc(1024*128/2);
  ushort_t* W2h = (ushort_t*)alloc(128*512/2);
  ushort_t* W2l = (ushort_t*)alloc(128*512/2);
  ushort_t* WgFh = (ushort_t*)alloc(G3*320/2);
  ushort_t* WgFl = (ushort_t*)alloc(G3*320/2);
  ushort_t* WgBh = (ushort_t*)alloc(G3*320/2);
  ushort_t* WgBl = (ushort_t*)alloc(G3*320/2);
  int* deg     = (int*)alloc(N_NODES + 4);
  int* row_ptr = (int*)alloc(N_NODES + 4);
  int* cursor  = (int*)alloc(N_NODES + 4);
  int* col     = (int*)alloc(E_EDGES + 4);
  float* xlr2 = xlr1;

  hipMemsetAsync(deg,    0, N_NODES * sizeof(int), stream);
  hipMemsetAsync(cursor, 0, N_NODES * sizeof(int), stream);
  hipMemsetAsync(lsum,   0, (size_t)N_NODES * 3 * sizeof(float), stream);
  hipMemsetAsync(gmean,  0, 512 * sizeof(float), stream);
  hipMemsetAsync(hbuf[0], 0, HTOT * sizeof(ushort_t), stream);  // hA hi
  hipMemsetAsync(hbuf[1], 0, HTOT * sizeof(ushort_t), stream);  // hA lo
  hipMemsetAsync(hbuf[4], 0, HTOT * sizeof(ushort_t), stream);  // hC hi
  hipMemsetAsync(hbuf[5], 0, HTOT * sizeof(ushort_t), stream);  // hC lo

  deg_loop_kernel<<<(E_EDGES + 255)/256, 256, 0, stream>>>(edst, eattr, deg, lsum);
  loop_div_kernel<<<(N_NODES + 255)/256, 256, 0, stream>>>(deg, lsum, lattr);
  scan_rowptr_kernel<<<1, 256, 0, stream>>>(deg, row_ptr);
  csr_fill_kernel<<<(E_EDGES + 255)/256, 256, 0, stream>>>(edst, row_ptr, cursor, col);
  build_emeta<<<(EF + 255)/256, 256, 0, stream>>>(eattr, lattr, esrc, emeta);
  split_arr<<<(int)((XTOT + 255)/256), 256, 0, stream>>>(x, xh, xlo, (long)XTOT);
  split_w_gat1<<<(1024*128 + 255)/256, 256, 0, stream>>>(g1_wl, g1_wr, W1h, W1l);
  split_w_gat2<<<(128*512 + 255)/256, 256, 0, stream>>>(g2_wl, g2_wr, W2h, W2l);
  split_w_gru<<<(G3*320 + 255)/256, 256, 0, stream>>>(wih_f, whh_f, WgFh, WgFl);
  split_w_gru<<<(G3*320 + 255)/256, 256, 0, stream>>>(wih_b, whh_b, WgBh, WgBl);

  const int MB32 = (N_NODES + 31) / 32;   // 313
  const int NODE_BLOCKS = (N_NODES + 3) / 4;
  for (int t = 0; t < T_SEQ; t++){
    const ushort_t* xth = xh  + (size_t)t * N_NODES * IN_CH;
    const ushort_t* xtl = xlo + (size_t)t * N_NODES * IN_CH;
    gemm_nolds<<<dim3(MB32, 4), 256, 0, stream>>>(xth, xtl, W1h, W1l, xlr1,
                                                  N_NODES, IN_CH, 1024);
    gat1_fused<<<NODE_BLOCKS, 256, 0, stream>>>(
        xlr1, emeta, row_ptr, col, g1_we, g1_att, g1_b, h1h, h1l);
    gemm_nolds<<<dim3(MB32, 1), 256, 0, stream>>>(h1h, h1l, W2h, W2l, xlr2,
                                                  N_NODES, HC, 128);
    gat2_fused<<<NODE_BLOCKS, 256, 0, stream>>>(
        xlr2, emeta, row_ptr, col, g2_we, g2_att, g2_b,
        embh + (size_t)t * N_NODES * HID, embl + (size_t)t * N_NODES * HID);
  }

  // GRU: both directions per launch; fwd ping-pong hbuf[0,1]<->[2,3], bwd [4,5]<->[6,7]
  {
    int fin = 0, bin = 4;
    for (int s = 0; s < T_SEQ; s++){
      int fo = fin ^ 2, bo = bin ^ 2;
      GruArgs ga;
      ga.EtH[0] = embh + (size_t)s * N_NODES * HID;
      ga.EtL[0] = embl + (size_t)s * N_NODES * HID;
      ga.EtH[1] = embh + (size_t)(T_SEQ - 1 - s) * N_NODES * HID;
      ga.EtL[1] = embl + (size_t)(T_SEQ - 1 - s) * N_NODES * HID;
      ga.WH[0] = WgFh; ga.WL[0] = WgFl; ga.WH[1] = WgBh; ga.WL[1] = WgBl;
      ga.BIH[0] = bih_f; ga.BHH[0] = bhh_f; ga.BIH[1] = bih_b; ga.BHH[1] = bhh_b;
      ga.HinH[0] = hbuf[fin];   ga.HinL[0] = hbuf[fin+1];
      ga.HinH[1] = hbuf[bin];   ga.HinL[1] = hbuf[bin+1];
      ga.HoutH[0] = hbuf[fo];   ga.HoutL[0] = hbuf[fo+1];
      ga.HoutH[1] = hbuf[bo];   ga.HoutL[1] = hbuf[bo+1];
      gru_nolds<<<dim3(MB32, 2, 2), 256, 0, stream>>>(ga);
      fin = fo; bin = bo;
    }
    // T_SEQ=32 even -> finals in hbuf[0,1] (fwd) and hbuf[4,5] (bwd)
  }

  mean_kernel<<<(N_NODES + 49)/50, 256, 0, stream>>>(hbuf[0], hbuf[1], hbuf[4], hbuf[5], gmean);
  fc_kernel<<<33, 64, 0, stream>>>(gmean, fc_w, fc_b, out);
}

// Round 7
// 7363.493 us; speedup vs baseline: 1.2244x; 1.2244x over previous
//
#include <hip/hip_runtime.h>

#define T_SEQ   32
#define N_NODES 10000
#define E_EDGES 160000
#define EF      (E_EDGES + N_NODES)
#define IN_CH   128
#define HID     64
#define HEADS   8
#define HC      512
#define GRU_H   256
#define G3      768

typedef __attribute__((ext_vector_type(8))) short short8;
typedef __attribute__((ext_vector_type(4))) float f32x4;
typedef unsigned short ushort_t;

__device__ __forceinline__ float wave_reduce_sum(float v){
#pragma unroll
  for (int off = 32; off; off >>= 1) v += __shfl_xor(v, off, 64);
  return v;
}

__device__ __forceinline__ ushort_t f2bf(float v){
  unsigned u = __float_as_uint(v);
  unsigned r = u + 0x7FFFu + ((u >> 16) & 1u);
  return (ushort_t)(r >> 16);
}
__device__ __forceinline__ float bf2f(ushort_t b){
  return __uint_as_float(((unsigned)b) << 16);
}

// ---------------- graph setup ----------------

__global__ __launch_bounds__(256)
void deg_loop_kernel(const int* __restrict__ edst, const float* __restrict__ eattr,
                     int* __restrict__ deg, float* __restrict__ lsum){
  int e = blockIdx.x * 256 + threadIdx.x;
  if (e < E_EDGES){
    int d = edst[e];
    atomicAdd(&deg[d], 1);
    atomicAdd(&lsum[d*3+0], eattr[e*3+0]);
    atomicAdd(&lsum[d*3+1], eattr[e*3+1]);
    atomicAdd(&lsum[d*3+2], eattr[e*3+2]);
  }
}

__global__ __launch_bounds__(256)
void loop_div_kernel(const int* __restrict__ deg, const float* __restrict__ lsum,
                     float* __restrict__ lattr){
  int n = blockIdx.x * 256 + threadIdx.x;
  if (n < N_NODES){
    float d = fmaxf((float)deg[n], 1.0f);
    lattr[n*3+0] = lsum[n*3+0] / d;
    lattr[n*3+1] = lsum[n*3+1] / d;
    lattr[n*3+2] = lsum[n*3+2] / d;
  }
}

__global__ __launch_bounds__(256)
void scan_rowptr_kernel(const int* __restrict__ deg, int* __restrict__ row_ptr){
  __shared__ int sums[256];
  __shared__ int base[256];
  int tid = threadIdx.x;
  const int CH = 40;
  int start = tid * CH;
  int s = 0;
  for (int k = 0; k < CH; k++){
    int n = start + k;
    if (n < N_NODES) s += deg[n];
  }
  sums[tid] = s;
  __syncthreads();
  if (tid == 0){
    int acc = 0;
    for (int i = 0; i < 256; i++){ base[i] = acc; acc += sums[i]; }
  }
  __syncthreads();
  int acc = base[tid];
  for (int k = 0; k < CH; k++){
    int n = start + k;
    if (n < N_NODES){ row_ptr[n] = acc; acc += deg[n]; }
    else if (n == N_NODES){ row_ptr[n] = acc; }
  }
}

__global__ __launch_bounds__(256)
void csr_fill_kernel(const int* __restrict__ edst, const int* __restrict__ row_ptr,
                     int* __restrict__ cursor, int* __restrict__ col){
  int e = blockIdx.x * 256 + threadIdx.x;
  if (e < E_EDGES){
    int d = edst[e];
    int pos = row_ptr[d] + atomicAdd(&cursor[d], 1);
    col[pos] = e;
  }
}

__global__ __launch_bounds__(256)
void build_emeta(const float* __restrict__ eattr, const float* __restrict__ lattr,
                 const int* __restrict__ esrc, float4* __restrict__ emeta){
  int e = blockIdx.x * 256 + threadIdx.x;
  if (e < E_EDGES){
    emeta[e] = make_float4(eattr[e*3], eattr[e*3+1], eattr[e*3+2], __int_as_float(esrc[e]));
  } else if (e < EF){
    int n = e - E_EDGES;
    emeta[e] = make_float4(lattr[n*3], lattr[n*3+1], lattr[n*3+2], __int_as_float(n));
  }
}

// ---------------- pre-split kernels ----------------

__global__ __launch_bounds__(256)
void split_arr(const float* __restrict__ src, ushort_t* __restrict__ hi,
               ushort_t* __restrict__ lo, long n){
  long idx = (long)blockIdx.x * 256 + threadIdx.x;
  if (idx < n){
    float v = src[idx];
    ushort_t h = f2bf(v);
    hi[idx] = h; lo[idx] = f2bf(v - bf2f(h));
  }
}

__global__ __launch_bounds__(256)
void split_w_gat1(const float* __restrict__ wl, const float* __restrict__ wr,
                  ushort_t* __restrict__ hi, ushort_t* __restrict__ lo){
  int idx = blockIdx.x * 256 + threadIdx.x;
  if (idx >= 1024 * 128) return;
  int n = idx >> 7, k = idx & 127;
  float v = (n < 512) ? wl[k * 512 + n] : wr[k * 512 + (n - 512)];
  ushort_t h = f2bf(v);
  hi[idx] = h; lo[idx] = f2bf(v - bf2f(h));
}

__global__ __launch_bounds__(256)
void split_w_gat2(const float* __restrict__ wl, const float* __restrict__ wr,
                  ushort_t* __restrict__ hi, ushort_t* __restrict__ lo){
  int idx = blockIdx.x * 256 + threadIdx.x;
  if (idx >= 128 * 512) return;
  int n = idx >> 9, k = idx & 511;
  float v = (n < 64) ? wl[k * 64 + n] : wr[k * 64 + (n - 64)];
  ushort_t h = f2bf(v);
  hi[idx] = h; lo[idx] = f2bf(v - bf2f(h));
}

// GRU weight pack: Wpk[jt][kc][r][32] with r = g*64 + jj; weight row g*256+jt*64+jj,
// k = kc*32 + kk; k<64 from wih, else whh. hi/lo split.
__global__ __launch_bounds__(256)
void pack_w_gru(const float* __restrict__ wih, const float* __restrict__ whh,
                ushort_t* __restrict__ hi, ushort_t* __restrict__ lo){
  int idx = blockIdx.x * 256 + threadIdx.x;
  if (idx >= 4 * 10 * 192 * 32) return;
  int kk = idx & 31;
  int r  = (idx >> 5) % 192;
  int kc = (idx >> 5) / 192 % 10;
  int jt = idx / (32 * 192 * 10);
  int g = r >> 6, jj = r & 63;
  int wrow = g * 256 + jt * 64 + jj;
  int k = kc * 32 + kk;
  float v = (k < 64) ? wih[wrow * 64 + k] : whh[wrow * 256 + (k - 64)];
  ushort_t h = f2bf(v);
  hi[idx] = h; lo[idx] = f2bf(v - bf2f(h));
}

// ------------- barrier-free bf16x3 GEMM (GAT path, weights tiny/L2-hot) ----

__global__ __launch_bounds__(256)
void gemm_nolds(const ushort_t* __restrict__ Ah, const ushort_t* __restrict__ Al,
                const ushort_t* __restrict__ Bh, const ushort_t* __restrict__ Bl,
                float* __restrict__ C, int M, int K, int N){
  int tid = threadIdx.x;
  int w = tid >> 6, lane = tid & 63;
  int m16 = lane & 15, quad = lane >> 4;
  int n0 = (blockIdx.y * 4 + w) * 64;
  if (n0 >= N) return;
  int m0 = blockIdx.x * 32;

  f32x4 acc[2][4];
#pragma unroll
  for (int i = 0; i < 2; i++)
#pragma unroll
    for (int j = 0; j < 4; j++) acc[i][j] = (f32x4){0,0,0,0};

  int ar0 = m0 + m16;      if (ar0 >= M) ar0 = M - 1;
  int ar1 = m0 + 16 + m16; if (ar1 >= M) ar1 = M - 1;
  const ushort_t* Ah0 = Ah + (size_t)ar0 * K + quad * 8;
  const ushort_t* Al0 = Al + (size_t)ar0 * K + quad * 8;
  const ushort_t* Ah1 = Ah + (size_t)ar1 * K + quad * 8;
  const ushort_t* Al1 = Al + (size_t)ar1 * K + quad * 8;

  for (int k0 = 0; k0 < K; k0 += 32){
    short8 a_h[2], a_l[2];
    a_h[0] = *(const short8*)(Ah0 + k0); a_l[0] = *(const short8*)(Al0 + k0);
    a_h[1] = *(const short8*)(Ah1 + k0); a_l[1] = *(const short8*)(Al1 + k0);
#pragma unroll
    for (int nt = 0; nt < 4; nt++){
      size_t boff = (size_t)(n0 + nt * 16 + m16) * K + k0 + quad * 8;
      short8 b_h = *(const short8*)(Bh + boff);
      short8 b_l = *(const short8*)(Bl + boff);
#pragma unroll
      for (int mt = 0; mt < 2; mt++){
        acc[mt][nt] = __builtin_amdgcn_mfma_f32_16x16x32_bf16(a_h[mt], b_h, acc[mt][nt],0,0,0);
        acc[mt][nt] = __builtin_amdgcn_mfma_f32_16x16x32_bf16(a_h[mt], b_l, acc[mt][nt],0,0,0);
        acc[mt][nt] = __builtin_amdgcn_mfma_f32_16x16x32_bf16(a_l[mt], b_h, acc[mt][nt],0,0,0);
      }
    }
  }
#pragma unroll
  for (int mt = 0; mt < 2; mt++){
    int row = m0 + mt * 16 + quad * 4;
#pragma unroll
    for (int nt = 0; nt < 4; nt++){
      int cc = n0 + nt * 16 + m16;
#pragma unroll
      for (int r4 = 0; r4 < 4; r4++){
        if (row + r4 < M) C[(size_t)(row + r4) * N + cc] = acc[mt][nt][r4];
      }
    }
  }
}

// ------------- LDS-staged fused GRU step, both directions ------------------
// Block: 64 nodes x 64 GRU cols (x 3 gates); 4 waves in 2x2; K chunks of 32.
// NOTE: all staging copies are short8 = 8 shorts = 16 B (ushort4 is only 8 B —
// that was the R5/R6 NaN bug: half of every staged LDS row was uninitialized).

#define LDK 40

struct GruArgs {
  const ushort_t *EtH[2], *EtL[2];     // [N][64]
  const ushort_t *WpH[2], *WpL[2];     // packed [4][10][192][32]
  const float    *BIH[2], *BHH[2];
  const ushort_t *HinH[2],*HinL[2];    // [N][256]
  ushort_t *HoutH[2], *HoutL[2];
};

__global__ __launch_bounds__(256)
void gru_step(GruArgs ga){
  int dir = blockIdx.z;
  const ushort_t* EtH  = ga.EtH[dir];  const ushort_t* EtL  = ga.EtL[dir];
  const ushort_t* WpH  = ga.WpH[dir];  const ushort_t* WpL  = ga.WpL[dir];
  const float*    BIH  = ga.BIH[dir];  const float*    BHH  = ga.BHH[dir];
  const ushort_t* HinH = ga.HinH[dir]; const ushort_t* HinL = ga.HinL[dir];
  ushort_t* HoutH = ga.HoutH[dir];     ushort_t* HoutL = ga.HoutL[dir];

  __shared__ __align__(16) short Ah_s[64 * LDK];
  __shared__ __align__(16) short Al_s[64 * LDK];
  __shared__ __align__(16) short Bh_s[192 * LDK];
  __shared__ __align__(16) short Bl_s[192 * LDK];

  int tid = threadIdx.x;
  int w = tid >> 6, lane = tid & 63;
  int wm = w >> 1, wn = w & 1;
  int m16 = lane & 15, quad = lane >> 4;
  int m0 = blockIdx.x * 64;
  int jt = blockIdx.y;               // j-tile of 64
  int j0 = jt * 64;

  int srow = tid >> 2;               // 0..63
  int sc   = (tid & 3) * 8;          // short offset 0,8,16,24
  int anode = m0 + srow; if (anode >= N_NODES) anode = N_NODES - 1;

  f32x4 acc[4][2][2];                // r, z, n_in, n_hid
#pragma unroll
  for (int g = 0; g < 4; g++)
#pragma unroll
    for (int i = 0; i < 2; i++)
#pragma unroll
      for (int j = 0; j < 2; j++) acc[g][i][j] = (f32x4){0,0,0,0};

  for (int kc = 0; kc < 10; kc++){
    int k0 = kc * 32;
    if (kc) __syncthreads();
    // stage A (hi, lo): 64 rows x 32 shorts; each thread one 16B chunk
    {
      const ushort_t *sh, *sl;
      if (k0 < 64){
        sh = EtH + (size_t)anode * 64 + k0 + sc;
        sl = EtL + (size_t)anode * 64 + k0 + sc;
      } else {
        sh = HinH + (size_t)anode * 256 + (k0 - 64) + sc;
        sl = HinL + (size_t)anode * 256 + (k0 - 64) + sc;
      }
      *(short8*)&Ah_s[srow * LDK + sc] = *(const short8*)sh;
      *(short8*)&Al_s[srow * LDK + sc] = *(const short8*)sl;
    }
    // stage B (hi, lo): 192 rows x 32 shorts = 768 16B chunks, 3 passes of 256
    {
      const ushort_t* bh = WpH + ((size_t)jt * 10 + kc) * 192 * 32;
      const ushort_t* bl = WpL + ((size_t)jt * 10 + kc) * 192 * 32;
      for (int i = tid; i < 768; i += 256){
        int r = i >> 2, c = (i & 3) * 8;
        *(short8*)&Bh_s[r * LDK + c] = *(const short8*)(bh + r * 32 + c);
        *(short8*)&Bl_s[r * LDK + c] = *(const short8*)(bl + r * 32 + c);
      }
    }
    __syncthreads();

    short8 a_h[2], a_l[2];
#pragma unroll
    for (int mt = 0; mt < 2; mt++){
      int r = wm * 32 + mt * 16 + m16;
      a_h[mt] = *(const short8*)&Ah_s[r * LDK + quad * 8];
      a_l[mt] = *(const short8*)&Al_s[r * LDK + quad * 8];
    }
#pragma unroll
    for (int g = 0; g < 3; g++){
      int tgt = (g < 2) ? g : (k0 < 64 ? 2 : 3);
#pragma unroll
      for (int nt = 0; nt < 2; nt++){
        int r = g * 64 + wn * 32 + nt * 16 + m16;
        short8 b_h = *(const short8*)&Bh_s[r * LDK + quad * 8];
        short8 b_l = *(const short8*)&Bl_s[r * LDK + quad * 8];
#pragma unroll
        for (int mt = 0; mt < 2; mt++){
          acc[tgt][mt][nt] = __builtin_amdgcn_mfma_f32_16x16x32_bf16(a_h[mt], b_h, acc[tgt][mt][nt],0,0,0);
          acc[tgt][mt][nt] = __builtin_amdgcn_mfma_f32_16x16x32_bf16(a_h[mt], b_l, acc[tgt][mt][nt],0,0,0);
          acc[tgt][mt][nt] = __builtin_amdgcn_mfma_f32_16x16x32_bf16(a_l[mt], b_h, acc[tgt][mt][nt],0,0,0);
        }
      }
    }
  }

#pragma unroll
  for (int mt = 0; mt < 2; mt++){
    int row = m0 + wm * 32 + mt * 16 + quad * 4;
#pragma unroll
    for (int nt = 0; nt < 2; nt++){
      int j = j0 + wn * 32 + nt * 16 + m16;
      float br  = BIH[j] + BHH[j];
      float bz  = BIH[GRU_H + j] + BHH[GRU_H + j];
      float bni = BIH[2*GRU_H + j];
      float bnh = BHH[2*GRU_H + j];
#pragma unroll
      for (int r4 = 0; r4 < 4; r4++){
        int node = row + r4;
        if (node < N_NODES){
          float rr = 1.f / (1.f + __expf(-(acc[0][mt][nt][r4] + br)));
          float zz = 1.f / (1.f + __expf(-(acc[1][mt][nt][r4] + bz)));
          float nn = tanhf(acc[2][mt][nt][r4] + bni + rr * (acc[3][mt][nt][r4] + bnh));
          size_t hidx = (size_t)node * GRU_H + j;
          float hold = bf2f(HinH[hidx]) + bf2f(HinL[hidx]);
          float hv = (1.f - zz) * nn + zz * hold;
          ushort_t hh = f2bf(hv);
          HoutH[hidx] = hh;
          HoutL[hidx] = f2bf(hv - bf2f(hh));
        }
      }
    }
  }
}

// ---------------- fused GAT layer 1 ----------------

__global__ __launch_bounds__(256)
void gat1_fused(const float* __restrict__ xlr, const float4* __restrict__ emeta,
                const int* __restrict__ row_ptr, const int* __restrict__ col,
                const float* __restrict__ we, const float* __restrict__ att,
                const float* __restrict__ bias,
                ushort_t* __restrict__ outh, ushort_t* __restrict__ outl){
  int n = (blockIdx.x * 256 + threadIdx.x) >> 6;
  int lane = threadIdx.x & 63;
  if (n >= N_NODES) return;
  int ch0 = lane * 4;
  int ch1 = 256 + lane * 4;

  float4 att0 = *(const float4*)&att[ch0];
  float4 att1 = *(const float4*)&att[ch1];
  float4 we00 = *(const float4*)&we[ch0],        we01 = *(const float4*)&we[ch1];
  float4 we10 = *(const float4*)&we[512 + ch0],  we11 = *(const float4*)&we[512 + ch1];
  float4 we20 = *(const float4*)&we[1024 + ch0], we21 = *(const float4*)&we[1024 + ch1];
  const float* xrow_n = xlr + (size_t)n * 1024;
  float4 xr0 = *(const float4*)&xrow_n[512 + ch0];
  float4 xr1 = *(const float4*)&xrow_n[512 + ch1];

  float den0 = 0.f, den1 = 0.f;
  float4 acc0 = make_float4(0,0,0,0), acc1 = make_float4(0,0,0,0);
  int beg = row_ptr[n], end = row_ptr[n + 1];

  float4 mt_c = emeta[E_EDGES + n];
  for (int p = beg - 1; p < end; p++){
    float4 mt_n = mt_c;
    if (p + 1 < end) mt_n = emeta[col[p + 1]];
    float a0 = mt_c.x, a1 = mt_c.y, a2 = mt_c.z;
    int s = __float_as_int(mt_c.w);
    const float* xrow = xlr + (size_t)s * 1024;
    float4 xl0 = *(const float4*)&xrow[ch0];
    float4 xl1 = *(const float4*)&xrow[ch1];
    {
      float vx = xl0.x + xr0.x + a0*we00.x + a1*we10.x + a2*we20.x;
      float vy = xl0.y + xr0.y + a0*we00.y + a1*we10.y + a2*we20.y;
      float vz = xl0.z + xr0.z + a0*we00.z + a1*we10.z + a2*we20.z;
      float vw = xl0.w + xr0.w + a0*we00.w + a1*we10.w + a2*we20.w;
      vx = fmaxf(vx, 0.2f*vx); vy = fmaxf(vy, 0.2f*vy);
      vz = fmaxf(vz, 0.2f*vz); vw = fmaxf(vw, 0.2f*vw);
      float pm = vx*att0.x + vy*att0.y + vz*att0.z + vw*att0.w;
      pm += __shfl_xor(pm, 1, 64); pm += __shfl_xor(pm, 2, 64);
      pm += __shfl_xor(pm, 4, 64); pm += __shfl_xor(pm, 8, 64);
      float wgt = __expf(pm);
      den0 += wgt;
      acc0.x += wgt * xl0.x; acc0.y += wgt * xl0.y;
      acc0.z += wgt * xl0.z; acc0.w += wgt * xl0.w;
    }
    {
      float vx = xl1.x + xr1.x + a0*we01.x + a1*we11.x + a2*we21.x;
      float vy = xl1.y + xr1.y + a0*we01.y + a1*we11.y + a2*we21.y;
      float vz = xl1.z + xr1.z + a0*we01.z + a1*we11.z + a2*we21.z;
      float vw = xl1.w + xr1.w + a0*we01.w + a1*we11.w + a2*we21.w;
      vx = fmaxf(vx, 0.2f*vx); vy = fmaxf(vy, 0.2f*vy);
      vz = fmaxf(vz, 0.2f*vz); vw = fmaxf(vw, 0.2f*vw);
      float pm = vx*att1.x + vy*att1.y + vz*att1.z + vw*att1.w;
      pm += __shfl_xor(pm, 1, 64); pm += __shfl_xor(pm, 2, 64);
      pm += __shfl_xor(pm, 4, 64); pm += __shfl_xor(pm, 8, 64);
      float wgt = __expf(pm);
      den1 += wgt;
      acc1.x += wgt * xl1.x; acc1.y += wgt * xl1.y;
      acc1.z += wgt * xl1.z; acc1.w += wgt * xl1.w;
    }
    mt_c = mt_n;
  }

  float4 b0 = *(const float4*)&bias[ch0];
  float4 b1 = *(const float4*)&bias[ch1];
  float id0 = 1.f / den0, id1 = 1.f / den1;
  float o[8];
  o[0] = acc0.x*id0 + b0.x; o[1] = acc0.y*id0 + b0.y;
  o[2] = acc0.z*id0 + b0.z; o[3] = acc0.w*id0 + b0.w;
  o[4] = acc1.x*id1 + b1.x; o[5] = acc1.y*id1 + b1.y;
  o[6] = acc1.z*id1 + b1.z; o[7] = acc1.w*id1 + b1.w;
  ushort4 h0, h1v, l0, l1v;
  ushort_t* hp0 = (ushort_t*)&h0; ushort_t* hp1 = (ushort_t*)&h1v;
  ushort_t* lp0 = (ushort_t*)&l0; ushort_t* lp1 = (ushort_t*)&l1v;
#pragma unroll
  for (int i = 0; i < 8; i++){
    float v = o[i];
    v = v > 0.f ? v : (__expf(v) - 1.f);
    ushort_t hh = f2bf(v);
    ushort_t ll = f2bf(v - bf2f(hh));
    if (i < 4){ hp0[i] = hh; lp0[i] = ll; } else { hp1[i-4] = hh; lp1[i-4] = ll; }
  }
  *(ushort4*)&outh[(size_t)n * 512 + ch0] = h0;
  *(ushort4*)&outh[(size_t)n * 512 + ch1] = h1v;
  *(ushort4*)&outl[(size_t)n * 512 + ch0] = l0;
  *(ushort4*)&outl[(size_t)n * 512 + ch1] = l1v;
}

// ---------------- fused GAT layer 2 ----------------

__global__ __launch_bounds__(256)
void gat2_fused(const float* __restrict__ xlr, const float4* __restrict__ emeta,
                const int* __restrict__ row_ptr, const int* __restrict__ col,
                const float* __restrict__ we, const float* __restrict__ att,
                const float* __restrict__ bias,
                ushort_t* __restrict__ outh, ushort_t* __restrict__ outl){
  int n = (blockIdx.x * 256 + threadIdx.x) >> 6;
  int lane = threadIdx.x & 63;
  if (n >= N_NODES) return;
  int g = lane >> 4;
  int c4 = (lane & 15) * 4;

  float4 attq = *(const float4*)&att[c4];
  float4 we0q = *(const float4*)&we[c4];
  float4 we1q = *(const float4*)&we[64 + c4];
  float4 we2q = *(const float4*)&we[128 + c4];
  float4 xr4  = *(const float4*)&xlr[(size_t)n * 128 + 64 + c4];

  float den = 0.f;
  float4 acc = make_float4(0,0,0,0);
  int beg = row_ptr[n], end = row_ptr[n + 1];

  for (int p0 = beg - 1; p0 < end; p0 += 4){
    int pp = p0 + g;
    bool valid = pp < end;
    int s = n; float a0 = 0.f, a1 = 0.f, a2 = 0.f;
    if (valid){
      float4 mt = (pp < beg) ? emeta[E_EDGES + n] : emeta[col[pp]];
      a0 = mt.x; a1 = mt.y; a2 = mt.z; s = __float_as_int(mt.w);
    }
    float4 xl4 = *(const float4*)&xlr[(size_t)s * 128 + c4];
    float vx = xl4.x + xr4.x + a0*we0q.x + a1*we1q.x + a2*we2q.x;
    float vy = xl4.y + xr4.y + a0*we0q.y + a1*we1q.y + a2*we2q.y;
    float vz = xl4.z + xr4.z + a0*we0q.z + a1*we1q.z + a2*we2q.z;
    float vw = xl4.w + xr4.w + a0*we0q.w + a1*we1q.w + a2*we2q.w;
    vx = fmaxf(vx, 0.2f*vx); vy = fmaxf(vy, 0.2f*vy);
    vz = fmaxf(vz, 0.2f*vz); vw = fmaxf(vw, 0.2f*vw);
    float pm = vx*attq.x + vy*attq.y + vz*attq.z + vw*attq.w;
    pm += __shfl_xor(pm, 1, 64); pm += __shfl_xor(pm, 2, 64);
    pm += __shfl_xor(pm, 4, 64); pm += __shfl_xor(pm, 8, 64);
    float wgt = valid ? __expf(pm) : 0.f;
    den += wgt;
    acc.x += wgt * xl4.x; acc.y += wgt * xl4.y;
    acc.z += wgt * xl4.z; acc.w += wgt * xl4.w;
  }
#pragma unroll
  for (int off = 16; off <= 32; off <<= 1){
    den   += __shfl_xor(den, off, 64);
    acc.x += __shfl_xor(acc.x, off, 64);
    acc.y += __shfl_xor(acc.y, off, 64);
    acc.z += __shfl_xor(acc.z, off, 64);
    acc.w += __shfl_xor(acc.w, off, 64);
  }
  if (g == 0){
    float4 bq = *(const float4*)&bias[c4];
    float id = 1.f / den;
    float o[4];
    o[0] = acc.x*id + bq.x; o[1] = acc.y*id + bq.y;
    o[2] = acc.z*id + bq.z; o[3] = acc.w*id + bq.w;
    ushort4 hv, lv;
    ushort_t* hp = (ushort_t*)&hv; ushort_t* lp = (ushort_t*)&lv;
#pragma unroll
    for (int i = 0; i < 4; i++){
      float v = o[i];
      v = v > 0.f ? v : (__expf(v) - 1.f);
      ushort_t hh = f2bf(v);
      hp[i] = hh; lp[i] = f2bf(v - bf2f(hh));
    }
    *(ushort4*)&outh[(size_t)n * 64 + c4] = hv;
    *(ushort4*)&outl[(size_t)n * 64 + c4] = lv;
  }
}

// ---------------- tail ----------------

__global__ __launch_bounds__(256)
void mean_kernel(const ushort_t* __restrict__ hfh, const ushort_t* __restrict__ hfl,
                 const ushort_t* __restrict__ hbh, const ushort_t* __restrict__ hbl,
                 float* __restrict__ g){
  int k = threadIdx.x;
  int n0 = blockIdx.x * 50;
  int n1 = n0 + 50; if (n1 > N_NODES) n1 = N_NODES;
  float sf = 0.f, sb = 0.f;
  for (int n = n0; n < n1; n++){
    size_t i = (size_t)n * GRU_H + k;
    sf += bf2f(hfh[i]) + bf2f(hfl[i]);
    sb += bf2f(hbh[i]) + bf2f(hbl[i]);
  }
  atomicAdd(&g[k], sf);
  atomicAdd(&g[GRU_H + k], sb);
}

__global__ __launch_bounds__(64)
void fc_kernel(const float* __restrict__ g, const float* __restrict__ W,
               const float* __restrict__ b, float* __restrict__ out){
  int j = blockIdx.x;
  int lane = threadIdx.x;
  float s = 0.f;
  for (int k = lane; k < 2 * GRU_H; k += 64) s += g[k] * W[j * (2 * GRU_H) + k];
  s = wave_reduce_sum(s);
  if (lane == 0) out[j] = b[j] + s * (1.0f / N_NODES);
}

// ---------------- launch ----------------

extern "C" void kernel_launch(void* const* d_in, const int* in_sizes, int n_in,
                              void* d_out, int out_size, void* d_ws, size_t ws_size,
                              hipStream_t stream){
  const float* x     = (const float*)d_in[0];
  const float* eattr = (const float*)d_in[1];
  const int*   esrc  = (const int*)  d_in[2];
  const int*   edst  = (const int*)  d_in[3];
  const float* g1_wl = (const float*)d_in[4];
  const float* g1_wr = (const float*)d_in[5];
  const float* g1_we = (const float*)d_in[6];
  const float* g1_att= (const float*)d_in[7];
  const float* g1_b  = (const float*)d_in[8];
  const float* g2_wl = (const float*)d_in[9];
  const float* g2_wr = (const float*)d_in[10];
  const float* g2_we = (const float*)d_in[11];
  const float* g2_att= (const float*)d_in[12];
  const float* g2_b  = (const float*)d_in[13];
  const float* wih_f = (const float*)d_in[14];
  const float* whh_f = (const float*)d_in[15];
  const float* bih_f = (const float*)d_in[16];
  const float* bhh_f = (const float*)d_in[17];
  const float* wih_b = (const float*)d_in[18];
  const float* whh_b = (const float*)d_in[19];
  const float* bih_b = (const float*)d_in[20];
  const float* bhh_b = (const float*)d_in[21];
  const float* fc_w  = (const float*)d_in[22];
  const float* fc_b  = (const float*)d_in[23];
  float* out = (float*)d_out;

  float* ws = (float*)d_ws;
  size_t o = 0;
  auto alloc = [&](size_t nfloats) -> float* {
    float* p = ws + o; o += (nfloats + 3) & ~(size_t)3; return p;
  };
  const size_t XTOT = (size_t)T_SEQ * N_NODES * IN_CH;
  ushort_t* xh   = (ushort_t*)alloc(XTOT / 2);
  ushort_t* xlo  = (ushort_t*)alloc(XTOT / 2);
  float* xlr1    = alloc((size_t)N_NODES * 1024);
  ushort_t* h1h  = (ushort_t*)alloc((size_t)N_NODES * 512 / 2 + 4);
  ushort_t* h1l  = (ushort_t*)alloc((size_t)N_NODES * 512 / 2 + 4);
  const size_t ETOT = (size_t)T_SEQ * N_NODES * HID;
  ushort_t* embh = (ushort_t*)alloc(ETOT / 2);
  ushort_t* embl = (ushort_t*)alloc(ETOT / 2);
  const size_t HTOT = (size_t)N_NODES * GRU_H;
  ushort_t* hbuf[8];
  for (int i = 0; i < 8; i++) hbuf[i] = (ushort_t*)alloc(HTOT / 2 + 4);
  float* lsum  = alloc((size_t)N_NODES * 3);
  float* lattr = alloc((size_t)N_NODES * 3);
  float* gmean = alloc(512);
  float4* emeta = (float4*)alloc((size_t)EF * 4);
  ushort_t* W1h = (ushort_t*)alloc(1024*128/2);
  ushort_t* W1l = (ushort_t*)alloc(1024*128/2);
  ushort_t* W2h = (ushort_t*)alloc(128*512/2);
  ushort_t* W2l = (ushort_t*)alloc(128*512/2);
  const size_t WPK = 4 * 10 * 192 * 32;     // 245760 shorts
  ushort_t* WpFh = (ushort_t*)alloc(WPK/2);
  ushort_t* WpFl = (ushort_t*)alloc(WPK/2);
  ushort_t* WpBh = (ushort_t*)alloc(WPK/2);
  ushort_t* WpBl = (ushort_t*)alloc(WPK/2);
  int* deg     = (int*)alloc(N_NODES + 4);
  int* row_ptr = (int*)alloc(N_NODES + 4);
  int* cursor  = (int*)alloc(N_NODES + 4);
  int* col     = (int*)alloc(E_EDGES + 4);
  float* xlr2 = xlr1;

  hipMemsetAsync(deg,    0, N_NODES * sizeof(int), stream);
  hipMemsetAsync(cursor, 0, N_NODES * sizeof(int), stream);
  hipMemsetAsync(lsum,   0, (size_t)N_NODES * 3 * sizeof(float), stream);
  hipMemsetAsync(gmean,  0, 512 * sizeof(float), stream);
  hipMemsetAsync(hbuf[0], 0, HTOT * sizeof(ushort_t), stream);
  hipMemsetAsync(hbuf[1], 0, HTOT * sizeof(ushort_t), stream);
  hipMemsetAsync(hbuf[4], 0, HTOT * sizeof(ushort_t), stream);
  hipMemsetAsync(hbuf[5], 0, HTOT * sizeof(ushort_t), stream);

  deg_loop_kernel<<<(E_EDGES + 255)/256, 256, 0, stream>>>(edst, eattr, deg, lsum);
  loop_div_kernel<<<(N_NODES + 255)/256, 256, 0, stream>>>(deg, lsum, lattr);
  scan_rowptr_kernel<<<1, 256, 0, stream>>>(deg, row_ptr);
  csr_fill_kernel<<<(E_EDGES + 255)/256, 256, 0, stream>>>(edst, row_ptr, cursor, col);
  build_emeta<<<(EF + 255)/256, 256, 0, stream>>>(eattr, lattr, esrc, emeta);
  split_arr<<<(int)((XTOT + 255)/256), 256, 0, stream>>>(x, xh, xlo, (long)XTOT);
  split_w_gat1<<<(1024*128 + 255)/256, 256, 0, stream>>>(g1_wl, g1_wr, W1h, W1l);
  split_w_gat2<<<(128*512 + 255)/256, 256, 0, stream>>>(g2_wl, g2_wr, W2h, W2l);
  pack_w_gru<<<(int)((WPK + 255)/256), 256, 0, stream>>>(wih_f, whh_f, WpFh, WpFl);
  pack_w_gru<<<(int)((WPK + 255)/256), 256, 0, stream>>>(wih_b, whh_b, WpBh, WpBl);

  const int MB32 = (N_NODES + 31) / 32;   // 313
  const int MB64 = (N_NODES + 63) / 64;   // 157
  const int NODE_BLOCKS = (N_NODES + 3) / 4;
  for (int t = 0; t < T_SEQ; t++){
    const ushort_t* xth = xh  + (size_t)t * N_NODES * IN_CH;
    const ushort_t* xtl = xlo + (size_t)t * N_NODES * IN_CH;
    gemm_nolds<<<dim3(MB32, 4), 256, 0, stream>>>(xth, xtl, W1h, W1l, xlr1,
                                                  N_NODES, IN_CH, 1024);
    gat1_fused<<<NODE_BLOCKS, 256, 0, stream>>>(
        xlr1, emeta, row_ptr, col, g1_we, g1_att, g1_b, h1h, h1l);
    gemm_nolds<<<dim3(MB32, 1), 256, 0, stream>>>(h1h, h1l, W2h, W2l, xlr2,
                                                  N_NODES, HC, 128);
    gat2_fused<<<NODE_BLOCKS, 256, 0, stream>>>(
        xlr2, emeta, row_ptr, col, g2_we, g2_att, g2_b,
        embh + (size_t)t * N_NODES * HID, embl + (size_t)t * N_NODES * HID);
  }

  // GRU: both directions per launch; fwd ping-pong hbuf[0,1]<->[2,3], bwd [4,5]<->[6,7]
  {
    int fin = 0, bin = 4;
    for (int s = 0; s < T_SEQ; s++){
      int fo = fin ^ 2, bo = bin ^ 2;
      GruArgs ga;
      ga.EtH[0] = embh + (size_t)s * N_NODES * HID;
      ga.EtL[0] = embl + (size_t)s * N_NODES * HID;
      ga.EtH[1] = embh + (size_t)(T_SEQ - 1 - s) * N_NODES * HID;
      ga.EtL[1] = embl + (size_t)(T_SEQ - 1 - s) * N_NODES * HID;
      ga.WpH[0] = WpFh; ga.WpL[0] = WpFl; ga.WpH[1] = WpBh; ga.WpL[1] = WpBl;
      ga.BIH[0] = bih_f; ga.BHH[0] = bhh_f; ga.BIH[1] = bih_b; ga.BHH[1] = bhh_b;
      ga.HinH[0] = hbuf[fin];   ga.HinL[0] = hbuf[fin+1];
      ga.HinH[1] = hbuf[bin];   ga.HinL[1] = hbuf[bin+1];
      ga.HoutH[0] = hbuf[fo];   ga.HoutL[0] = hbuf[fo+1];
      ga.HoutH[1] = hbuf[bo];   ga.HoutL[1] = hbuf[bo+1];
      gru_step<<<dim3(MB64, 4, 2), 256, 0, stream>>>(ga);
      fin = fo; bin = bo;
    }
  }

  mean_kernel<<<(N_NODES + 49)/50, 256, 0, stream>>>(hbuf[0], hbuf[1], hbuf[4], hbuf[5], gmean);
  fc_kernel<<<33, 64, 0, stream>>>(gmean, fc_w, fc_b, out);
}